// Round 14
// baseline (117.437 us; speedup 1.0000x reference)
//
#include <hip/hip_runtime.h>
#include <cstdint>

#define P 7
#define PP 49
#define IMG 64
#define PIX 4096
#define XSTR 72    // LDS row stride: 288B, 16B-aligned rows -> b128 merging
#define XROWS 28   // xs tile rows: x rows q*16-6 .. q*16+21
#define MROWS 22   // ms tile rows: maps1 rows q*16-3 .. q*16+18

// fence: only ALU/VALU may cross -> DS reads and SMEM loads stay pinned to
// their region (bounded liveness + prefetch placement holds)
#define FENCE __builtin_amdgcn_sched_barrier(0x3);

// ---- two 10-float window row sets (named scalars; alternate per row) ----
#define DECLRQ \
    float r0,r1,r2,r3,r4,r5,r6,r7,r8,r9; \
    float q0,q1,q2,q3,q4,q5,q6,q7,q8,q9;

#define LDR(BP) { const float* _p=(BP); r0=_p[0];r1=_p[1];r2=_p[2];r3=_p[3];r4=_p[4];r5=_p[5];r6=_p[6];r7=_p[7];r8=_p[8];r9=_p[9]; }
#define LDQ(BP) { const float* _p=(BP); q0=_p[0];q1=_p[1];q2=_p[2];q3=_p[3];q4=_p[4];q5=_p[5];q6=_p[6];q7=_p[7];q8=_p[8];q9=_p[9]; }

// per-row sums: px p uses cols p..p+6, j-ascending (bit-identical to r9-r13)
#define SUMR \
    s0+=r0; s1+=r1; s2+=r2; s3+=r3; \
    s0+=r1; s1+=r2; s2+=r3; s3+=r4; \
    s0+=r2; s1+=r3; s2+=r4; s3+=r5; \
    s0+=r3; s1+=r4; s2+=r5; s3+=r6; \
    s0+=r4; s1+=r5; s2+=r6; s3+=r7; \
    s0+=r5; s1+=r6; s2+=r7; s3+=r8; \
    s0+=r6; s1+=r7; s2+=r8; s3+=r9;
#define SUMQ \
    s0+=q0; s1+=q1; s2+=q2; s3+=q3; \
    s0+=q1; s1+=q2; s2+=q3; s3+=q4; \
    s0+=q2; s1+=q3; s2+=q4; s3+=q5; \
    s0+=q3; s1+=q4; s2+=q5; s3+=q6; \
    s0+=q4; s1+=q5; s2+=q6; s3+=q7; \
    s0+=q5; s1+=q6; s2+=q7; s3+=q8; \
    s0+=q6; s1+=q7; s2+=q8; s3+=q9;

// pipelined sum pass: load row i+1 while summing row i (rows ascending)
#define SUMPASS(B) \
    LDR((B)+0*XSTR) FENCE \
    LDQ((B)+1*XSTR) FENCE \
    SUMR FENCE \
    LDR((B)+2*XSTR) FENCE \
    SUMQ FENCE \
    LDQ((B)+3*XSTR) FENCE \
    SUMR FENCE \
    LDR((B)+4*XSTR) FENCE \
    SUMQ FENCE \
    LDQ((B)+5*XSTR) FENCE \
    SUMR FENCE \
    LDR((B)+6*XSTR) FENCE \
    SUMQ FENCE \
    SUMR

// ---- uniform scalar weight access (s_load; K$-resident) ----
#define W1G(K) W1[(K)*8 + l]

// ---- stage 1 tap: weight is an SGPR scalar, double-buffered u0/u1 ----
#define S1C(W,RA,RB,RC,RD) \
    a0=fmaf(W,(RA)-mu0,a0); a1=fmaf(W,(RB)-mu1,a1); \
    a2=fmaf(W,(RC)-mu2,a2); a3=fmaf(W,(RD)-mu3,a3); FENCE

#define S1ROW_E(i, ROWPF) \
    u1 = W1G((i)*7+1); ROWPF S1C(u0, r0,r1,r2,r3) \
    u0 = W1G((i)*7+2); S1C(u1, r1,r2,r3,r4) \
    u1 = W1G((i)*7+3); S1C(u0, r2,r3,r4,r5) \
    u0 = W1G((i)*7+4); S1C(u1, r3,r4,r5,r6) \
    u1 = W1G((i)*7+5); S1C(u0, r4,r5,r6,r7) \
    u0 = W1G((i)*7+6); S1C(u1, r5,r6,r7,r8) \
    u1 = W1G((i)*7+7); S1C(u0, r6,r7,r8,r9)
#define S1ROW_O(i, ROWPF) \
    u0 = W1G((i)*7+1); ROWPF S1C(u1, q0,q1,q2,q3) \
    u1 = W1G((i)*7+2); S1C(u0, q1,q2,q3,q4) \
    u0 = W1G((i)*7+3); S1C(u1, q2,q3,q4,q5) \
    u1 = W1G((i)*7+4); S1C(u0, q3,q4,q5,q6) \
    u0 = W1G((i)*7+5); S1C(u1, q4,q5,q6,q7) \
    u1 = W1G((i)*7+6); S1C(u0, q5,q6,q7,q8) \
    u0 = W1G((i)*7+7); S1C(u1, q6,q7,q8,q9)
// last row: no prefetch past tap 48 (W1 has 49*8 floats)
#define S1ROW6 \
    u1 = W1G(43); S1C(u0, r0,r1,r2,r3) \
    u0 = W1G(44); S1C(u1, r1,r2,r3,r4) \
    u1 = W1G(45); S1C(u0, r2,r3,r4,r5) \
    u0 = W1G(46); S1C(u1, r3,r4,r5,r6) \
    u1 = W1G(47); S1C(u0, r4,r5,r6,r7) \
    u0 = W1G(48); S1C(u1, r5,r6,r7,r8) \
    S1C(u0, r6,r7,r8,r9)
#define NOPF

// ---- stage 2: 8 SGPR weights per tap, 2 sets (e/f), prefetch 1 tap ahead --
#define S2PFE(T) \
    e0=W2[(T)*8+0]; e1=W2[(T)*8+1]; e2=W2[(T)*8+2]; e3=W2[(T)*8+3]; \
    e4=W2[(T)*8+4]; e5=W2[(T)*8+5]; e6=W2[(T)*8+6]; e7=W2[(T)*8+7];
#define S2PFF(T) \
    f0=W2[(T)*8+0]; f1=W2[(T)*8+1]; f2=W2[(T)*8+2]; f3=W2[(T)*8+3]; \
    f4=W2[(T)*8+4]; f5=W2[(T)*8+5]; f6=W2[(T)*8+6]; f7=W2[(T)*8+7];

// fmaf order identical to r11-r13: filters ascending, pixels a,b,c,d
#define S2C(w0_,w1_,w2_,w3_,w4_,w5_,w6_,w7_,RA,RB,RC,RD) { \
    const float t0=(RA)-mu0, t1=(RB)-mu1, t2=(RC)-mu2, t3=(RD)-mu3; \
    a0=fmaf(w0_,t0,a0); b0=fmaf(w0_,t1,b0); c0=fmaf(w0_,t2,c0); d0=fmaf(w0_,t3,d0); \
    a1=fmaf(w1_,t0,a1); b1=fmaf(w1_,t1,b1); c1=fmaf(w1_,t2,c1); d1=fmaf(w1_,t3,d1); \
    a2=fmaf(w2_,t0,a2); b2=fmaf(w2_,t1,b2); c2=fmaf(w2_,t2,c2); d2=fmaf(w2_,t3,d2); \
    a3=fmaf(w3_,t0,a3); b3=fmaf(w3_,t1,b3); c3=fmaf(w3_,t2,c3); d3=fmaf(w3_,t3,d3); \
    a4=fmaf(w4_,t0,a4); b4=fmaf(w4_,t1,b4); c4=fmaf(w4_,t2,c4); d4=fmaf(w4_,t3,d4); \
    a5=fmaf(w5_,t0,a5); b5=fmaf(w5_,t1,b5); c5=fmaf(w5_,t2,c5); d5=fmaf(w5_,t3,d5); \
    a6=fmaf(w6_,t0,a6); b6=fmaf(w6_,t1,b6); c6=fmaf(w6_,t2,c6); d6=fmaf(w6_,t3,d6); \
    a7=fmaf(w7_,t0,a7); b7=fmaf(w7_,t1,b7); c7=fmaf(w7_,t2,c7); d7=fmaf(w7_,t3,d7); } FENCE
#define S2CE(RA,RB,RC,RD) S2C(e0,e1,e2,e3,e4,e5,e6,e7, RA,RB,RC,RD)
#define S2CF(RA,RB,RC,RD) S2C(f0,f1,f2,f3,f4,f5,f6,f7, RA,RB,RC,RD)

#define S2ROW_E(i, ROWPF) \
    S2PFF((i)*7+1) ROWPF S2CE(r0,r1,r2,r3) \
    S2PFE((i)*7+2) S2CF(r1,r2,r3,r4) \
    S2PFF((i)*7+3) S2CE(r2,r3,r4,r5) \
    S2PFE((i)*7+4) S2CF(r3,r4,r5,r6) \
    S2PFF((i)*7+5) S2CE(r4,r5,r6,r7) \
    S2PFE((i)*7+6) S2CF(r5,r6,r7,r8) \
    S2PFF((i)*7+7) S2CE(r6,r7,r8,r9)
#define S2ROW_O(i, ROWPF) \
    S2PFE((i)*7+1) ROWPF S2CF(q0,q1,q2,q3) \
    S2PFF((i)*7+2) S2CE(q1,q2,q3,q4) \
    S2PFE((i)*7+3) S2CF(q2,q3,q4,q5) \
    S2PFF((i)*7+4) S2CE(q3,q4,q5,q6) \
    S2PFE((i)*7+5) S2CF(q4,q5,q6,q7) \
    S2PFF((i)*7+6) S2CE(q5,q6,q7,q8) \
    S2PFE((i)*7+7) S2CF(q6,q7,q8,q9)
// last row: taps 42..48; no prefetch past tap 48 (W2 has 49*8 floats)
#define S2ROW6 \
    S2PFF(43) S2CE(r0,r1,r2,r3) \
    S2PFE(44) S2CF(r1,r2,r3,r4) \
    S2PFF(45) S2CE(r2,r3,r4,r5) \
    S2PFE(46) S2CF(r3,r4,r5,r6) \
    S2PFF(47) S2CE(r4,r5,r6,r7) \
    S2PFE(48) S2CF(r5,r6,r7,r8) \
    S2CE(r6,r7,r8,r9)

// ---------------------------------------------------------------------------
// One block per (channel, row-quarter): 2048 blocks x 256 threads.
// r11 structure; change: weights sourced via uniform SCALAR loads (s_load,
// K$-resident) with a 16-float double buffer prefetched one tap ahead --
// removes 98 b128 + 49 b32 DS broadcasts per wave (DS pipe was binding).
// Per-pixel fmaf sequence unchanged -> bit-identical (absmax 0 since r9).
// ---------------------------------------------------------------------------
__global__ __launch_bounds__(256, 4) void stage_kernel(
    const float* __restrict__ x,    // [64][64][64]
    const float* __restrict__ W1,   // [49][8]
    const float* __restrict__ W2,   // [49][8]
    uint8_t* __restrict__ codes)    // [512][4096]
{
    __shared__ __align__(16) float xs[XROWS * XSTR];
    __shared__ __align__(16) float ms[MROWS * XSTR];

    const int b    = blockIdx.x;
    const int ch   = b >> 2;
    const int q16  = (b & 3) * 16;
    const int l    = ch >> 6;
    const int img  = ch & 63;
    const int tid  = threadIdx.x;

    // zero ms (stage-2 SAME padding: pad cols + out-of-image rows stay 0)
    #pragma unroll 1
    for (int i = tid; i < MROWS * XSTR; i += 256) ms[i] = 0.f;

    // load xs zero-padded (xs col c <-> x col c-3; xs row r <-> x row q16-6+r)
    const float* xb = x + (size_t)img * PIX;
    #pragma unroll 1
    for (int idx = tid; idx < XROWS * XSTR; idx += 256) {
        int r  = idx / XSTR, c = idx - r * XSTR;
        int gr = q16 - 6 + r, gc = c - 3;
        float v = 0.f;
        if (gr >= 0 && gr < IMG && gc >= 0 && gc < IMG)
            v = xb[gr * IMG + gc];
        xs[idx] = v;
    }
    __syncthreads();

    // ---- stage 1: 22 ms-rows x 16 col-strips = 352 strips (4 px each) ----
    #pragma unroll 1
    for (int it = 0; it < 2; ++it) {
        int s = tid + it * 256;
        if (s < MROWS * 16) {
            const int row = s >> 4;           // ms row 0..21
            const int cs4 = (s & 15) * 4;     // pixel col 0..60
            const float* bp = &xs[row * XSTR + cs4];
            DECLRQ
            float s0 = 0.f, s1 = 0.f, s2 = 0.f, s3 = 0.f;
            SUMPASS(bp)
            const float mu0 = s0 / 49.0f, mu1 = s1 / 49.0f;
            const float mu2 = s2 / 49.0f, mu3 = s3 / 49.0f;
            float a0 = 0.f, a1 = 0.f, a2 = 0.f, a3 = 0.f;
            float u0, u1;
            LDR(bp + 0*XSTR) u0 = W1G(0); FENCE
            S1ROW_E(0, LDQ(bp + 1*XSTR))
            S1ROW_O(1, LDR(bp + 2*XSTR))
            S1ROW_E(2, LDQ(bp + 3*XSTR))
            S1ROW_O(3, LDR(bp + 4*XSTR))
            S1ROW_E(4, LDQ(bp + 5*XSTR))
            S1ROW_O(5, LDR(bp + 6*XSTR))
            S1ROW6
            const int gm = q16 - 3 + row;
            const bool in_img = (gm >= 0) && (gm < IMG);
            float* mp = &ms[row * XSTR + 3 + cs4];
            mp[0] = in_img ? a0 : 0.f;
            mp[1] = in_img ? a1 : 0.f;
            mp[2] = in_img ? a2 : 0.f;
            mp[3] = in_img ? a3 : 0.f;
        }
    }
    __syncthreads();

    // ---- stage 2 + code bits: 16 rows x 16 col-strips = 256 strips ----
    {
        const int rr  = tid >> 4;             // out row 0..15
        const int cs4 = (tid & 15) * 4;       // pixel col 0..60
        const float* bp = &ms[rr * XSTR + cs4];
        DECLRQ
        float s0 = 0.f, s1 = 0.f, s2 = 0.f, s3 = 0.f;
        SUMPASS(bp)
        const float mu0 = s0 / 49.0f, mu1 = s1 / 49.0f;
        const float mu2 = s2 / 49.0f, mu3 = s3 / 49.0f;
        float a0=0.f,a1=0.f,a2=0.f,a3=0.f,a4=0.f,a5=0.f,a6=0.f,a7=0.f;
        float b0=0.f,b1=0.f,b2=0.f,b3=0.f,b4=0.f,b5=0.f,b6=0.f,b7=0.f;
        float c0=0.f,c1=0.f,c2=0.f,c3=0.f,c4=0.f,c5=0.f,c6=0.f,c7=0.f;
        float d0=0.f,d1=0.f,d2=0.f,d3=0.f,d4=0.f,d5=0.f,d6=0.f,d7=0.f;
        float e0,e1,e2,e3,e4,e5,e6,e7;
        float f0,f1,f2,f3,f4,f5,f6,f7;
        LDR(bp + 0*XSTR) S2PFE(0) FENCE
        S2ROW_E(0, LDQ(bp + 1*XSTR))
        S2ROW_O(1, LDR(bp + 2*XSTR))
        S2ROW_E(2, LDQ(bp + 3*XSTR))
        S2ROW_O(3, LDR(bp + 4*XSTR))
        S2ROW_E(4, LDQ(bp + 5*XSTR))
        S2ROW_O(5, LDR(bp + 6*XSTR))
        S2ROW6
        uint32_t k0 = 0, k1 = 0, k2 = 0, k3 = 0;
        k0 |= (a0>0.f)?128u:0u; k1 |= (b0>0.f)?128u:0u; k2 |= (c0>0.f)?128u:0u; k3 |= (d0>0.f)?128u:0u;
        k0 |= (a1>0.f)? 64u:0u; k1 |= (b1>0.f)? 64u:0u; k2 |= (c1>0.f)? 64u:0u; k3 |= (d1>0.f)? 64u:0u;
        k0 |= (a2>0.f)? 32u:0u; k1 |= (b2>0.f)? 32u:0u; k2 |= (c2>0.f)? 32u:0u; k3 |= (d2>0.f)? 32u:0u;
        k0 |= (a3>0.f)? 16u:0u; k1 |= (b3>0.f)? 16u:0u; k2 |= (c3>0.f)? 16u:0u; k3 |= (d3>0.f)? 16u:0u;
        k0 |= (a4>0.f)?  8u:0u; k1 |= (b4>0.f)?  8u:0u; k2 |= (c4>0.f)?  8u:0u; k3 |= (d4>0.f)?  8u:0u;
        k0 |= (a5>0.f)?  4u:0u; k1 |= (b5>0.f)?  4u:0u; k2 |= (c5>0.f)?  4u:0u; k3 |= (d5>0.f)?  4u:0u;
        k0 |= (a6>0.f)?  2u:0u; k1 |= (b6>0.f)?  2u:0u; k2 |= (c6>0.f)?  2u:0u; k3 |= (d6>0.f)?  2u:0u;
        k0 |= (a7>0.f)?  1u:0u; k1 |= (b7>0.f)?  1u:0u; k2 |= (c7>0.f)?  1u:0u; k3 |= (d7>0.f)?  1u:0u;
        uint32_t packed = k0 | (k1 << 8) | (k2 << 16) | (k3 << 24);
        *(uint32_t*)(codes + (size_t)ch * PIX + (q16 + rr) * 64 + cs4) = packed;
    }
}

// ---------------------------------------------------------------------------
// Kernel B: histogram + entropy (unchanged, ~4 us)
// ---------------------------------------------------------------------------
#define CPB 32

__global__ __launch_bounds__(256) void hist_kernel(
    const uint8_t* __restrict__ codes,  // [512][4096]
    float* __restrict__ out)            // [49*256][512]
{
    __shared__ uint32_t hist[256 * 33];

    const int bid   = blockIdx.x;       // 0..783
    const int cgrp  = bid & 15;
    const int nb    = bid >> 4;         // 0..48
    const int bi    = nb / 7, bj = nb - bi * 7;
    const int tid   = threadIdx.x;
    const int cbase = cgrp * CPB;

    for (int i = tid; i < 256 * 33; i += 256) hist[i] = 0;
    __syncthreads();

    const int cl  = tid >> 3;           // 0..31
    const int sub = tid & 7;            // 0..7
    const uint8_t* cp = codes + (size_t)(cbase + cl) * PIX;
    #pragma unroll
    for (int rr = 0; rr < 2; ++rr) {
        int row = bi * 8 + (sub * 2 + rr);
        const uint8_t* rp = cp + row * 64 + bj * 8;
        uint64_t v0 = *(const uint64_t*)(rp);
        uint64_t v1 = *(const uint64_t*)(rp + 8);
        #pragma unroll
        for (int t = 0; t < 8; ++t)
            atomicAdd(&hist[(uint32_t)((v0 >> (8 * t)) & 255u) * 33 + cl], 1u);
        #pragma unroll
        for (int t = 0; t < 8; ++t)
            atomicAdd(&hist[(uint32_t)((v1 >> (8 * t)) & 255u) * 33 + cl], 1u);
    }
    __syncthreads();

    const int lane_c = tid & 31;
    const int bin0   = tid >> 5;        // 0..7
    for (int i = 0; i < 32; ++i) {
        int bin = i * 8 + bin0;
        uint32_t cnt = hist[bin * 33 + lane_c];
        float ent = 0.f;
        if (cnt > 0) {
            float pz = (float)cnt * (1.0f / 256.0f);
            ent = -pz * log2f(pz);
        }
        out[((size_t)(nb * 256 + bin)) * 512 + cbase + lane_c] = ent;
    }
}

extern "C" void kernel_launch(void* const* d_in, const int* in_sizes, int n_in,
                              void* d_out, int out_size, void* d_ws, size_t ws_size,
                              hipStream_t stream) {
    const float* x  = (const float*)d_in[0];
    const float* W1 = (const float*)d_in[1];
    const float* W2 = (const float*)d_in[2];
    float* out = (float*)d_out;
    uint8_t* codes = (uint8_t*)d_ws;   // 512*4096 = 2 MB

    stage_kernel<<<2048, 256, 0, stream>>>(x, W1, W2, codes);
    hist_kernel<<<784, 256, 0, stream>>>(codes, out);
}

// Round 15
// 66.196 us; speedup vs baseline: 1.7741x; 1.7741x over previous
//
#include <hip/hip_runtime.h>
#include <cstdint>

#define P 7
#define PP 49
#define IMG 64
#define PIX 4096
#define XSTR 72    // LDS row stride: 288B, 16B-aligned rows -> b128 merging
#define XROWS 28   // xs tile rows: x rows q*16-6 .. q*16+21
#define MROWS 22   // ms tile rows: maps1 rows q*16-3 .. q*16+18

// fence: only ALU/VALU may cross -> DS reads stay pinned to their region
#define FENCE __builtin_amdgcn_sched_barrier(0x3);
#define NOPF

// ======================= stage-2: 4-px strips (r11, unchanged) ============
#define DECLRQ \
    float r0,r1,r2,r3,r4,r5,r6,r7,r8,r9; \
    float q0,q1,q2,q3,q4,q5,q6,q7,q8,q9;

#define LDR(BP) { const float* _p=(BP); r0=_p[0];r1=_p[1];r2=_p[2];r3=_p[3];r4=_p[4];r5=_p[5];r6=_p[6];r7=_p[7];r8=_p[8];r9=_p[9]; }
#define LDQ(BP) { const float* _p=(BP); q0=_p[0];q1=_p[1];q2=_p[2];q3=_p[3];q4=_p[4];q5=_p[5];q6=_p[6];q7=_p[7];q8=_p[8];q9=_p[9]; }

#define SUMR \
    s0+=r0; s1+=r1; s2+=r2; s3+=r3; \
    s0+=r1; s1+=r2; s2+=r3; s3+=r4; \
    s0+=r2; s1+=r3; s2+=r4; s3+=r5; \
    s0+=r3; s1+=r4; s2+=r5; s3+=r6; \
    s0+=r4; s1+=r5; s2+=r6; s3+=r7; \
    s0+=r5; s1+=r6; s2+=r7; s3+=r8; \
    s0+=r6; s1+=r7; s2+=r8; s3+=r9;
#define SUMQ \
    s0+=q0; s1+=q1; s2+=q2; s3+=q3; \
    s0+=q1; s1+=q2; s2+=q3; s3+=q4; \
    s0+=q2; s1+=q3; s2+=q4; s3+=q5; \
    s0+=q3; s1+=q4; s2+=q5; s3+=q6; \
    s0+=q4; s1+=q5; s2+=q6; s3+=q7; \
    s0+=q5; s1+=q6; s2+=q7; s3+=q8; \
    s0+=q6; s1+=q7; s2+=q8; s3+=q9;

#define SUMPASS(B) \
    LDR((B)+0*XSTR) FENCE \
    LDQ((B)+1*XSTR) FENCE \
    SUMR FENCE \
    LDR((B)+2*XSTR) FENCE \
    SUMQ FENCE \
    LDQ((B)+3*XSTR) FENCE \
    SUMR FENCE \
    LDR((B)+4*XSTR) FENCE \
    SUMQ FENCE \
    LDQ((B)+5*XSTR) FENCE \
    SUMR FENCE \
    LDR((B)+6*XSTR) FENCE \
    SUMQ FENCE \
    SUMR

#define S2T(i,j,RA,RB,RC,RD) { \
    const float t0 = (RA)-mu0, t1 = (RB)-mu1, t2 = (RC)-mu2, t3 = (RD)-mu3; \
    const float4 wA = *(const float4*)&w2s[((i)*7+(j))*8]; \
    const float4 wB = *(const float4*)&w2s[((i)*7+(j))*8 + 4]; \
    a0=fmaf(wA.x,t0,a0); b0=fmaf(wA.x,t1,b0); c0=fmaf(wA.x,t2,c0); d0=fmaf(wA.x,t3,d0); \
    a1=fmaf(wA.y,t0,a1); b1=fmaf(wA.y,t1,b1); c1=fmaf(wA.y,t2,c1); d1=fmaf(wA.y,t3,d1); \
    a2=fmaf(wA.z,t0,a2); b2=fmaf(wA.z,t1,b2); c2=fmaf(wA.z,t2,c2); d2=fmaf(wA.z,t3,d2); \
    a3=fmaf(wA.w,t0,a3); b3=fmaf(wA.w,t1,b3); c3=fmaf(wA.w,t2,c3); d3=fmaf(wA.w,t3,d3); \
    a4=fmaf(wB.x,t0,a4); b4=fmaf(wB.x,t1,b4); c4=fmaf(wB.x,t2,c4); d4=fmaf(wB.x,t3,d4); \
    a5=fmaf(wB.y,t0,a5); b5=fmaf(wB.y,t1,b5); c5=fmaf(wB.y,t2,c5); d5=fmaf(wB.y,t3,d5); \
    a6=fmaf(wB.z,t0,a6); b6=fmaf(wB.z,t1,b6); c6=fmaf(wB.z,t2,c6); d6=fmaf(wB.z,t3,d6); \
    a7=fmaf(wB.w,t0,a7); b7=fmaf(wB.w,t1,b7); c7=fmaf(wB.w,t2,c7); d7=fmaf(wB.w,t3,d7); \
    FENCE }
#define S2ROWS(i, B) { LDR((B) + (i)*XSTR) FENCE \
    S2T(i,0,r0,r1,r2,r3) S2T(i,1,r1,r2,r3,r4) S2T(i,2,r2,r3,r4,r5) \
    S2T(i,3,r3,r4,r5,r6) S2T(i,4,r4,r5,r6,r7) S2T(i,5,r5,r6,r7,r8) \
    S2T(i,6,r6,r7,r8,r9) }
#define S2ALL(B) S2ROWS(0,B) S2ROWS(1,B) S2ROWS(2,B) S2ROWS(3,B) \
                 S2ROWS(4,B) S2ROWS(5,B) S2ROWS(6,B)

// ======================= stage-1: 2-px strips (NEW: 704 strips, 3 iters) ==
#define DECL8 \
    float r0,r1,r2,r3,r4,r5,r6,r7; \
    float q0,q1,q2,q3,q4,q5,q6,q7;
#define LDR8(BP) { const float* _p=(BP); r0=_p[0];r1=_p[1];r2=_p[2];r3=_p[3];r4=_p[4];r5=_p[5];r6=_p[6];r7=_p[7]; }
#define LDQ8(BP) { const float* _p=(BP); q0=_p[0];q1=_p[1];q2=_p[2];q3=_p[3];q4=_p[4];q5=_p[5];q6=_p[6];q7=_p[7]; }

// px0 sums cols 0..6, px1 cols 1..7, j-ascending (same per-px order as r11)
#define SUM2R \
    s0+=r0; s1+=r1;  s0+=r1; s1+=r2;  s0+=r2; s1+=r3;  s0+=r3; s1+=r4; \
    s0+=r4; s1+=r5;  s0+=r5; s1+=r6;  s0+=r6; s1+=r7;
#define SUM2Q \
    s0+=q0; s1+=q1;  s0+=q1; s1+=q2;  s0+=q2; s1+=q3;  s0+=q3; s1+=q4; \
    s0+=q4; s1+=q5;  s0+=q5; s1+=q6;  s0+=q6; s1+=q7;

#define SUMPASS2(B) \
    LDR8((B)+0*XSTR) FENCE \
    LDQ8((B)+1*XSTR) FENCE \
    SUM2R FENCE \
    LDR8((B)+2*XSTR) FENCE \
    SUM2Q FENCE \
    LDQ8((B)+3*XSTR) FENCE \
    SUM2R FENCE \
    LDR8((B)+4*XSTR) FENCE \
    SUM2Q FENCE \
    LDQ8((B)+5*XSTR) FENCE \
    SUM2R FENCE \
    LDR8((B)+6*XSTR) FENCE \
    SUM2Q FENCE \
    SUM2R

#define S1C2(W,RA,RB) { const float w_ = (W); \
    a0 = fmaf(w_, (RA)-mu0, a0); a1 = fmaf(w_, (RB)-mu1, a1); FENCE }
#define S1ROW8_E(i, ROWPF) ROWPF \
    S1C2(w1s[(i)*7+0], r0,r1) S1C2(w1s[(i)*7+1], r1,r2) \
    S1C2(w1s[(i)*7+2], r2,r3) S1C2(w1s[(i)*7+3], r3,r4) \
    S1C2(w1s[(i)*7+4], r4,r5) S1C2(w1s[(i)*7+5], r5,r6) \
    S1C2(w1s[(i)*7+6], r6,r7)
#define S1ROW8_O(i, ROWPF) ROWPF \
    S1C2(w1s[(i)*7+0], q0,q1) S1C2(w1s[(i)*7+1], q1,q2) \
    S1C2(w1s[(i)*7+2], q2,q3) S1C2(w1s[(i)*7+3], q3,q4) \
    S1C2(w1s[(i)*7+4], q4,q5) S1C2(w1s[(i)*7+5], q5,q6) \
    S1C2(w1s[(i)*7+6], q6,q7)

// ---------------------------------------------------------------------------
// One block per (channel, row-quarter): 2048 blocks x 256 threads.
// r11 structure; change: stage-1 uses 2-px strips -> 704 strips over 3
// iterations (92% slot use vs 69% with 4-px/2-iter). Stage-2 unchanged
// (256 strips = exactly 1/thread). Per-pixel op order bit-identical.
// ---------------------------------------------------------------------------
__global__ __launch_bounds__(256, 4) void stage_kernel(
    const float* __restrict__ x,    // [64][64][64]
    const float* __restrict__ W1,   // [49][8]
    const float* __restrict__ W2,   // [49][8]
    uint8_t* __restrict__ codes)    // [512][4096]
{
    __shared__ __align__(16) float xs[XROWS * XSTR];
    __shared__ __align__(16) float ms[MROWS * XSTR];
    __shared__ float w1s[PP];
    __shared__ __align__(16) float w2s[PP * 8];

    const int b    = blockIdx.x;
    const int ch   = b >> 2;
    const int q16  = (b & 3) * 16;
    const int l    = ch >> 6;
    const int img  = ch & 63;
    const int tid  = threadIdx.x;

    // stage weights into LDS (all threads cover all elements)
    if (tid < PP) w1s[tid] = W1[tid * 8 + l];
    #pragma unroll 1
    for (int i = tid; i < PP * 8; i += 256) w2s[i] = W2[i];

    // zero ms (stage-2 SAME padding: pad cols + out-of-image rows stay 0)
    #pragma unroll 1
    for (int i = tid; i < MROWS * XSTR; i += 256) ms[i] = 0.f;

    // load xs zero-padded (xs col c <-> x col c-3; xs row r <-> x row q16-6+r)
    const float* xb = x + (size_t)img * PIX;
    #pragma unroll 1
    for (int idx = tid; idx < XROWS * XSTR; idx += 256) {
        int r  = idx / XSTR, c = idx - r * XSTR;
        int gr = q16 - 6 + r, gc = c - 3;
        float v = 0.f;
        if (gr >= 0 && gr < IMG && gc >= 0 && gc < IMG)
            v = xb[gr * IMG + gc];
        xs[idx] = v;
    }
    __syncthreads();

    // ---- stage 1: 22 ms-rows x 32 col-strips = 704 strips (2 px each) ----
    #pragma unroll 1
    for (int it = 0; it < 3; ++it) {
        int s = tid + it * 256;
        if (s < MROWS * 32) {
            const int row = s >> 5;           // ms row 0..21
            const int cs2 = (s & 31) * 2;     // pixel col 0..62
            const float* bp = &xs[row * XSTR + cs2];
            DECL8
            float s0 = 0.f, s1 = 0.f;
            SUMPASS2(bp)
            const float mu0 = s0 / 49.0f, mu1 = s1 / 49.0f;
            float a0 = 0.f, a1 = 0.f;
            LDR8(bp + 0*XSTR) FENCE
            S1ROW8_E(0, LDQ8(bp + 1*XSTR))
            S1ROW8_O(1, LDR8(bp + 2*XSTR))
            S1ROW8_E(2, LDQ8(bp + 3*XSTR))
            S1ROW8_O(3, LDR8(bp + 4*XSTR))
            S1ROW8_E(4, LDQ8(bp + 5*XSTR))
            S1ROW8_O(5, LDR8(bp + 6*XSTR))
            S1ROW8_E(6, NOPF)
            const int gm = q16 - 3 + row;
            const bool in_img = (gm >= 0) && (gm < IMG);
            float* mp = &ms[row * XSTR + 3 + cs2];
            mp[0] = in_img ? a0 : 0.f;
            mp[1] = in_img ? a1 : 0.f;
        }
    }
    __syncthreads();

    // ---- stage 2 + code bits: 16 rows x 16 col-strips = 256 strips ----
    {
        const int rr  = tid >> 4;             // out row 0..15
        const int cs4 = (tid & 15) * 4;       // pixel col 0..60
        const float* bp = &ms[rr * XSTR + cs4];
        DECLRQ
        float s0 = 0.f, s1 = 0.f, s2 = 0.f, s3 = 0.f;
        SUMPASS(bp)
        const float mu0 = s0 / 49.0f, mu1 = s1 / 49.0f;
        const float mu2 = s2 / 49.0f, mu3 = s3 / 49.0f;
        float a0=0.f,a1=0.f,a2=0.f,a3=0.f,a4=0.f,a5=0.f,a6=0.f,a7=0.f;
        float b0=0.f,b1=0.f,b2=0.f,b3=0.f,b4=0.f,b5=0.f,b6=0.f,b7=0.f;
        float c0=0.f,c1=0.f,c2=0.f,c3=0.f,c4=0.f,c5=0.f,c6=0.f,c7=0.f;
        float d0=0.f,d1=0.f,d2=0.f,d3=0.f,d4=0.f,d5=0.f,d6=0.f,d7=0.f;
        S2ALL(bp)
        uint32_t k0 = 0, k1 = 0, k2 = 0, k3 = 0;
        k0 |= (a0>0.f)?128u:0u; k1 |= (b0>0.f)?128u:0u; k2 |= (c0>0.f)?128u:0u; k3 |= (d0>0.f)?128u:0u;
        k0 |= (a1>0.f)? 64u:0u; k1 |= (b1>0.f)? 64u:0u; k2 |= (c1>0.f)? 64u:0u; k3 |= (d1>0.f)? 64u:0u;
        k0 |= (a2>0.f)? 32u:0u; k1 |= (b2>0.f)? 32u:0u; k2 |= (c2>0.f)? 32u:0u; k3 |= (d2>0.f)? 32u:0u;
        k0 |= (a3>0.f)? 16u:0u; k1 |= (b3>0.f)? 16u:0u; k2 |= (c3>0.f)? 16u:0u; k3 |= (d3>0.f)? 16u:0u;
        k0 |= (a4>0.f)?  8u:0u; k1 |= (b4>0.f)?  8u:0u; k2 |= (c4>0.f)?  8u:0u; k3 |= (d4>0.f)?  8u:0u;
        k0 |= (a5>0.f)?  4u:0u; k1 |= (b5>0.f)?  4u:0u; k2 |= (c5>0.f)?  4u:0u; k3 |= (d5>0.f)?  4u:0u;
        k0 |= (a6>0.f)?  2u:0u; k1 |= (b6>0.f)?  2u:0u; k2 |= (c6>0.f)?  2u:0u; k3 |= (d6>0.f)?  2u:0u;
        k0 |= (a7>0.f)?  1u:0u; k1 |= (b7>0.f)?  1u:0u; k2 |= (c7>0.f)?  1u:0u; k3 |= (d7>0.f)?  1u:0u;
        uint32_t packed = k0 | (k1 << 8) | (k2 << 16) | (k3 << 24);
        *(uint32_t*)(codes + (size_t)ch * PIX + (q16 + rr) * 64 + cs4) = packed;
    }
}

// ---------------------------------------------------------------------------
// Kernel B: histogram + entropy (unchanged; at the WRITE roofline ~4 us)
// ---------------------------------------------------------------------------
#define CPB 32

__global__ __launch_bounds__(256) void hist_kernel(
    const uint8_t* __restrict__ codes,  // [512][4096]
    float* __restrict__ out)            // [49*256][512]
{
    __shared__ uint32_t hist[256 * 33];

    const int bid   = blockIdx.x;       // 0..783
    const int cgrp  = bid & 15;
    const int nb    = bid >> 4;         // 0..48
    const int bi    = nb / 7, bj = nb - bi * 7;
    const int tid   = threadIdx.x;
    const int cbase = cgrp * CPB;

    for (int i = tid; i < 256 * 33; i += 256) hist[i] = 0;
    __syncthreads();

    const int cl  = tid >> 3;           // 0..31
    const int sub = tid & 7;            // 0..7
    const uint8_t* cp = codes + (size_t)(cbase + cl) * PIX;
    #pragma unroll
    for (int rr = 0; rr < 2; ++rr) {
        int row = bi * 8 + (sub * 2 + rr);
        const uint8_t* rp = cp + row * 64 + bj * 8;
        uint64_t v0 = *(const uint64_t*)(rp);
        uint64_t v1 = *(const uint64_t*)(rp + 8);
        #pragma unroll
        for (int t = 0; t < 8; ++t)
            atomicAdd(&hist[(uint32_t)((v0 >> (8 * t)) & 255u) * 33 + cl], 1u);
        #pragma unroll
        for (int t = 0; t < 8; ++t)
            atomicAdd(&hist[(uint32_t)((v1 >> (8 * t)) & 255u) * 33 + cl], 1u);
    }
    __syncthreads();

    const int lane_c = tid & 31;
    const int bin0   = tid >> 5;        // 0..7
    for (int i = 0; i < 32; ++i) {
        int bin = i * 8 + bin0;
        uint32_t cnt = hist[bin * 33 + lane_c];
        float ent = 0.f;
        if (cnt > 0) {
            float pz = (float)cnt * (1.0f / 256.0f);
            ent = -pz * log2f(pz);
        }
        out[((size_t)(nb * 256 + bin)) * 512 + cbase + lane_c] = ent;
    }
}

extern "C" void kernel_launch(void* const* d_in, const int* in_sizes, int n_in,
                              void* d_out, int out_size, void* d_ws, size_t ws_size,
                              hipStream_t stream) {
    const float* x  = (const float*)d_in[0];
    const float* W1 = (const float*)d_in[1];
    const float* W2 = (const float*)d_in[2];
    float* out = (float*)d_out;
    uint8_t* codes = (uint8_t*)d_ws;   // 512*4096 = 2 MB

    stage_kernel<<<2048, 256, 0, stream>>>(x, W1, W2, codes);
    hist_kernel<<<784, 256, 0, stream>>>(codes, out);
}